// Round 9
// baseline (124046.045 us; speedup 1.0000x reference)
//
#include <hip/hip_runtime.h>
#include <math.h>

// ============================================================================
// LARNN forward, MI355X — persistent kernel, 6 phases/step, fence-free sc1.
// ALL-F32 (bf16 diverges — chaotic recurrence, round 2). Deterministic BN.
// Round 9 = round-7 skeleton (512 thr, conflict-free As[m][k] staging)
//   + register ring-prefetch GEMM (A 4 slabs / B 2 slabs ahead, 1 sync/slab)
//   + x-GEMMs one step ahead, in-block-BN gates, symmetric flag barrier.
// Round-8 regression root-caused: transposed A-store (243M bank conflicts)
// + 256-thread blocks (4 waves/CU). Both reverted here.
// ============================================================================

#define T_  128
#define B_  256
#define F_  128
#define H_  512
#define W_  16
#define H4_ 2048
#define EPS_ 1e-5f
#define BH_ (B_*H_)
#define NBLK 256
#define NTHR 512
#define FSTRIDE 32

typedef __attribute__((ext_vector_type(4))) float f4;
typedef __attribute__((ext_vector_type(2))) float f2;
typedef unsigned long long u64;

__device__ __forceinline__ float eluf(float x){ return x > 0.f ? x : expf(x) - 1.f; }
__device__ __forceinline__ float sigf(float x){ return 1.f / (1.f + expf(-x)); }

// ---- LLC-coherent (sc1) relaxed accessors ----
__device__ __forceinline__ f4 ld_c(const float* p) {
  union { f4 v; u64 q[2]; } u;
  u.q[0] = __hip_atomic_load((const u64*)p,     __ATOMIC_RELAXED, __HIP_MEMORY_SCOPE_AGENT);
  u.q[1] = __hip_atomic_load((const u64*)p + 1, __ATOMIC_RELAXED, __HIP_MEMORY_SCOPE_AGENT);
  return u.v;
}
__device__ __forceinline__ void st_c(float* p, f4 v) {
  union { f4 v; u64 q[2]; } u; u.v = v;
  __hip_atomic_store((u64*)p,     u.q[0], __ATOMIC_RELAXED, __HIP_MEMORY_SCOPE_AGENT);
  __hip_atomic_store((u64*)p + 1, u.q[1], __ATOMIC_RELAXED, __HIP_MEMORY_SCOPE_AGENT);
}
__device__ __forceinline__ float ldf_c(const float* p) {
  unsigned u = __hip_atomic_load((const unsigned*)p, __ATOMIC_RELAXED, __HIP_MEMORY_SCOPE_AGENT);
  return __uint_as_float(u);
}
__device__ __forceinline__ void stf_c(float* p, float v) {
  __hip_atomic_store((unsigned*)p, __float_as_uint(v), __ATOMIC_RELAXED, __HIP_MEMORY_SCOPE_AGENT);
}

struct Params {
  const float *x, *W_ih, *b_ih, *W_hh, *Wq_in, *bq_in, *Wq, *bq, *Wk, *bk,
              *Wv, *bv, *Wo, *bo, *W_ac, *b_ac, *g_att, *be_att, *g_post, *be_post;
  float *out, *c, *h, *q, *Qh, *ctx, *attp, *preHF, *Kbuf, *Vbuf, *stA;
  float *preXb0, *preXb1, *qXb0, *qXb1;
  unsigned *arr;
};

// Symmetric flag barrier: thread i polls block i's flag. No RMW, no fences.
__device__ __forceinline__ void gbar(unsigned* arr, unsigned g) {
  asm volatile("s_waitcnt vmcnt(0) lgkmcnt(0)" ::: "memory");
  __syncthreads();
  if (threadIdx.x == 0)
    __hip_atomic_store(&arr[blockIdx.x * FSTRIDE], g, __ATOMIC_RELAXED, __HIP_MEMORY_SCOPE_AGENT);
  if (threadIdx.x < NBLK) {
    while (__hip_atomic_load(&arr[threadIdx.x * FSTRIDE], __ATOMIC_RELAXED, __HIP_MEMORY_SCOPE_AGENT) < g)
      __builtin_amdgcn_s_sleep(2);
  }
  __syncthreads();
}

// ---------------------------------------------------------------------------
// 64x64 tile, K = NS*32, 512 threads, 2x4 microtile (round-7 layout).
// A staged row-major As[64][36] (conflict-free); B row-major Bs[32][68].
// Register ring-prefetch: A 4 slabs ahead, B 2 ahead; ONE sync per slab.
// ---------------------------------------------------------------------------
struct GP {
  const float* A; int lda; int a_sc1;
  const float* W;               // [K][N] row-major (plain, L2-cached)
  const float* b1; const float* b2;
  const float* addm;            // sc1, stride N
  int doElu; int doNorm;
  float* out;                   // sc1, stride N
  float* stats; int mIdx;
  int N; int m0; int n0;
};

template<int NS>
__device__ void gemm64(const GP& J, int tid,
                       float (*AsL)[64][36], float (*BsL)[32][68],
                       const float* scl, const float* shf) {
  const int arow = tid >> 3, akq = (tid & 7) * 4;   // A stage: 1 f4/thread
  const int bkk = tid >> 4, bnn = (tid & 15) * 4;   // B stage: 1 f4/thread
  const int ty = tid >> 4, tx = tid & 15;           // microtile 2x4

  const float* aBase = J.A + (size_t)(J.m0 + arow) * J.lda + akq;
  const float* wBase = J.W + (size_t)bkk * J.N + J.n0 + bnn;
  const size_t wSlab = (size_t)32 * J.N;

  f4 ar[4], br[2];
  #pragma unroll
  for (int p = 0; p < 4; ++p)
    if (p < NS) ar[p] = J.a_sc1 ? ld_c(aBase + p * 32) : *(const f4*)(aBase + p * 32);
  #pragma unroll
  for (int p = 0; p < 2; ++p)
    if (p < NS) br[p] = *(const f4*)(wBase + p * wSlab);

  f4 am0, am1;
  if (J.addm) {
    am0 = ld_c(J.addm + (size_t)(J.m0 + ty * 2)     * J.N + J.n0 + tx * 4);
    am1 = ld_c(J.addm + (size_t)(J.m0 + ty * 2 + 1) * J.N + J.n0 + tx * 4);
  }

  float acc[2][4] = {{0.f,0.f,0.f,0.f},{0.f,0.f,0.f,0.f}};

  #pragma unroll 1
  for (int so = 0; so < NS; so += 4) {
    #pragma unroll
    for (int si = 0; si < 4 && si < NS; ++si) {
      const int s = so + si;
      const int buf = si & 1;
      // stage A slab s (norm applied here if requested)
      {
        f4 v = ar[si];
        if (J.doNorm) {
          #pragma unroll
          for (int i = 0; i < 4; ++i) {
            int gk = s * 32 + akq + i;
            v[i] = v[i] * scl[gk] + shf[gk];
          }
        }
        *(f4*)&AsL[buf][arow][akq] = v;
      }
      if (s + 4 < NS)
        ar[si] = J.a_sc1 ? ld_c(aBase + (s + 4) * 32) : *(const f4*)(aBase + (s + 4) * 32);
      *(f4*)&BsL[buf][bkk][bnn] = br[si & 1];
      if (s + 2 < NS)
        br[si & 1] = *(const f4*)(wBase + (size_t)(s + 2) * wSlab);
      __syncthreads();
      #pragma unroll
      for (int k = 0; k < 32; k += 2) {
        f2 a0 = *(const f2*)&AsL[buf][ty * 2][k];
        f2 a1 = *(const f2*)&AsL[buf][ty * 2 + 1][k];
        f4 b0 = *(const f4*)&BsL[buf][k][tx * 4];
        f4 b1 = *(const f4*)&BsL[buf][k + 1][tx * 4];
        #pragma unroll
        for (int j = 0; j < 4; ++j) {
          acc[0][j] = fmaf(a0[0], b0[j], acc[0][j]);
          acc[0][j] = fmaf(a0[1], b1[j], acc[0][j]);
          acc[1][j] = fmaf(a1[0], b0[j], acc[1][j]);
          acc[1][j] = fmaf(a1[1], b1[j], acc[1][j]);
        }
      }
    }
  }

  const int r0 = J.m0 + ty * 2, c0 = J.n0 + tx * 4;
  f4 bias = {0.f, 0.f, 0.f, 0.f};
  if (J.b1) bias += *(const f4*)(J.b1 + c0);
  if (J.b2) bias += *(const f4*)(J.b2 + c0);
  f4 v0, v1;
  #pragma unroll
  for (int j = 0; j < 4; ++j) { v0[j] = acc[0][j] + bias[j]; v1[j] = acc[1][j] + bias[j]; }
  if (J.addm) { v0 += am0; v1 += am1; }
  if (J.doElu) {
    #pragma unroll
    for (int j = 0; j < 4; ++j) { v0[j] = eluf(v0[j]); v1[j] = eluf(v1[j]); }
  }
  st_c(J.out + (size_t)r0 * J.N + c0, v0);
  st_c(J.out + (size_t)(r0 + 1) * J.N + c0, v1);

  if (J.stats) {   // deterministic per-64-row-tile column partials
    float* Af = (float*)AsL;
    float* Bf = (float*)BsL;
    __syncthreads();
    #pragma unroll
    for (int j = 0; j < 4; ++j) {
      Af[ty * 64 + tx * 4 + j] = v0[j] + v1[j];
      Bf[ty * 64 + tx * 4 + j] = v0[j] * v0[j] + v1[j] * v1[j];
    }
    __syncthreads();
    if (tid < 64) {
      float S = 0.f, Q = 0.f;
      #pragma unroll
      for (int y = 0; y < 32; ++y) { S += Af[y * 64 + tid]; Q += Bf[y * 64 + tid]; }
      stf_c(J.stats + J.mIdx * 1024 + J.n0 + tid, S);
      stf_c(J.stats + J.mIdx * 1024 + 512 + J.n0 + tid, Q);
    }
  }
}

__global__ __launch_bounds__(NTHR, 1) void larnn(Params P) {
  __shared__ float AsL[2][64][36];
  __shared__ float BsL[2][32][68];
  __shared__ float scl[H_], shf[H_];
  __shared__ float Qs[H_];
  __shared__ float sc_[8][16], aw_[8][16];

  const int bid = blockIdx.x, tid = threadIdx.x;
  unsigned g = 0;

  f4 creg = {0.f, 0.f, 0.f, 0.f};   // gates blocks: c[r][gc+sub*4..+3]

  // ---------- phase 0: preX(0), qX(0) ----------
  if (bid < 128) {
    GP J{}; J.A = P.x; J.lda = F_; J.a_sc1 = 0; J.W = P.W_ih;
    J.b1 = P.b_ih; J.b2 = P.b_ac; J.out = P.preXb0; J.N = H4_;
    J.m0 = (bid >> 5) * 64; J.n0 = (bid & 31) * 64;
    gemm64<4>(J, tid, AsL, BsL, scl, shf);
  } else if (bid < 160) {
    int l = bid - 128;
    GP J{}; J.A = P.x; J.lda = F_; J.a_sc1 = 0; J.W = P.Wq_in;
    J.b1 = P.bq_in; J.out = P.qXb0; J.N = H_;
    J.m0 = (l >> 3) * 64; J.n0 = (l & 7) * 64;
    gemm64<4>(J, tid, AsL, BsL, scl, shf);
  }
  gbar(P.arr, ++g);

  for (int t = 0; t < T_; ++t) {
    const int slot = (t - 1) & 15;
    float* preX  = (t & 1) ? P.preXb1 : P.preXb0;
    float* qX    = (t & 1) ? P.qXb1 : P.qXb0;
    float* preXn = (t & 1) ? P.preXb0 : P.preXb1;
    float* qXn   = (t & 1) ? P.qXb0 : P.qXb1;

    // ---------- PhA: q | K | V | preHF ----------
    if (bid < 32) {
      GP J{}; J.A = P.h; J.lda = H_; J.a_sc1 = 1;
      J.W = P.Wq_in + (size_t)F_ * H_; J.addm = qX; J.doElu = 1;
      J.out = P.q; J.N = H_;
      J.m0 = (bid >> 3) * 64; J.n0 = (bid & 7) * 64;
      gemm64<16>(J, tid, AsL, BsL, scl, shf);
    } else if (bid < 64) {
      int l = bid - 32;
      GP J{}; J.A = P.c; J.lda = H_; J.a_sc1 = 1;
      J.W = P.Wk; J.b1 = P.bk; J.doElu = 1;
      J.out = P.Kbuf + (size_t)slot * BH_; J.N = H_;
      J.m0 = (l >> 3) * 64; J.n0 = (l & 7) * 64;
      gemm64<16>(J, tid, AsL, BsL, scl, shf);
    } else if (bid < 96) {
      int l = bid - 64;
      GP J{}; J.A = P.c; J.lda = H_; J.a_sc1 = 1;
      J.W = P.Wv; J.b1 = P.bv; J.doElu = 1;
      J.out = P.Vbuf + (size_t)slot * BH_; J.N = H_;
      J.m0 = (l >> 3) * 64; J.n0 = (l & 7) * 64;
      gemm64<16>(J, tid, AsL, BsL, scl, shf);
    } else if (bid < 224) {
      int l = bid - 96;
      GP J{}; J.A = P.h; J.lda = H_; J.a_sc1 = 1;
      J.W = P.W_hh; J.addm = preX;
      J.out = P.preHF; J.N = H4_;
      J.m0 = (l >> 5) * 64; J.n0 = (l & 31) * 64;
      gemm64<16>(J, tid, AsL, BsL, scl, shf);
    }
    gbar(P.arr, ++g);

    // ---------- PhB: Qh | preX(t+1) | qX(t+1) ----------
    if (bid < 32) {
      GP J{}; J.A = P.q; J.lda = H_; J.a_sc1 = 1;
      J.W = P.Wq; J.b1 = P.bq;
      J.out = P.Qh; J.N = H_;
      J.m0 = (bid >> 3) * 64; J.n0 = (bid & 7) * 64;
      gemm64<16>(J, tid, AsL, BsL, scl, shf);
    } else if (bid < 160 && t + 1 < T_) {
      int l = bid - 32;
      GP J{}; J.A = P.x + (size_t)(t + 1) * B_ * F_; J.lda = F_; J.a_sc1 = 0;
      J.W = P.W_ih; J.b1 = P.b_ih; J.b2 = P.b_ac;
      J.out = preXn; J.N = H4_;
      J.m0 = (l >> 5) * 64; J.n0 = (l & 31) * 64;
      gemm64<4>(J, tid, AsL, BsL, scl, shf);
    } else if (bid < 192 && t + 1 < T_) {
      int l = bid - 160;
      GP J{}; J.A = P.x + (size_t)(t + 1) * B_ * F_; J.lda = F_; J.a_sc1 = 0;
      J.W = P.Wq_in; J.b1 = P.bq_in;
      J.out = qXn; J.N = H_;
      J.m0 = (l >> 3) * 64; J.n0 = (l & 7) * 64;
      gemm64<4>(J, tid, AsL, BsL, scl, shf);
    }
    gbar(P.arr, ++g);

    // ---------- PhC: attention (block = batch row; round-7 code) ----------
    {
      const int b = bid;
      const int nv = (t + 1 < W_) ? t + 1 : W_;
      if (tid < 128) *(f4*)&Qs[tid * 4] = ld_c(P.Qh + (size_t)b * H_ + tid * 4);
      __syncthreads();
      {
        const int p = tid >> 2, l4 = tid & 3;
        const int hh = p >> 4, w = p & 15;
        if (w < nv) {
          const int sl = (t - 1 - w) & 15;
          const float* kp = P.Kbuf + ((size_t)sl * B_ + b) * H_ + hh * 64 + l4 * 16;
          const float* qp = Qs + hh * 64 + l4 * 16;
          float s = 0.f;
          #pragma unroll
          for (int d = 0; d < 16; d += 4) {
            f4 kv = ld_c(kp + d);
            f4 qv = *(const f4*)(qp + d);
            s = fmaf(kv[0], qv[0], fmaf(kv[1], qv[1], fmaf(kv[2], qv[2], fmaf(kv[3], qv[3], s))));
          }
          s += __shfl_xor(s, 1); s += __shfl_xor(s, 2);
          if (l4 == 0) sc_[hh][w] = s * 0.125f;
        }
      }
      __syncthreads();
      if (tid < 8) {
        float mx = -1e30f;
        for (int w = 0; w < nv; ++w) mx = fmaxf(mx, sc_[tid][w]);
        float ss = 0.f;
        for (int w = 0; w < nv; ++w) { float e = expf(sc_[tid][w] - mx); aw_[tid][w] = e; ss += e; }
        float inv = 1.f / ss;
        for (int w = 0; w < nv; ++w) aw_[tid][w] *= inv;
      }
      __syncthreads();
      {
        const int j = tid, hh = j >> 6;
        float o = 0.f;
        for (int w = 0; w < nv; ++w) {
          const int sl = (t - 1 - w) & 15;
          o = fmaf(aw_[hh][w], ldf_c(P.Vbuf + ((size_t)sl * B_ + b) * H_ + j), o);
        }
        stf_c(P.ctx + (size_t)b * H_ + j, o);
      }
    }
    gbar(P.arr, ++g);

    // ---------- PhD: attp = elu(ctx@Wo + bo) + BN partials ----------
    if (bid < 32) {
      GP J{}; J.A = P.ctx; J.lda = H_; J.a_sc1 = 1;
      J.W = P.Wo; J.b1 = P.bo; J.doElu = 1;
      J.out = P.attp; J.stats = P.stA; J.N = H_;
      J.m0 = (bid >> 3) * 64; J.n0 = (bid & 7) * 64; J.mIdx = J.m0 >> 6;
      gemm64<16>(J, tid, AsL, BsL, scl, shf);
    }
    gbar(P.arr, ++g);

    // ---------- PhE: preHF += BN(attp) @ W_ac ----------
    if (bid < 128) {
      if (tid < H_) {
        float S = ldf_c(P.stA + tid) + ldf_c(P.stA + 1024 + tid)
                + ldf_c(P.stA + 2048 + tid) + ldf_c(P.stA + 3072 + tid);
        float Q = ldf_c(P.stA + 512 + tid) + ldf_c(P.stA + 1536 + tid)
                + ldf_c(P.stA + 2560 + tid) + ldf_c(P.stA + 3584 + tid);
        float mu = S * (1.f / B_), var = Q * (1.f / B_) - mu * mu;
        float sc = rsqrtf(var + EPS_) * P.g_att[tid];
        scl[tid] = sc; shf[tid] = P.be_att[tid] - mu * sc;
      }
      __syncthreads();
      GP J{}; J.A = P.attp; J.lda = H_; J.a_sc1 = 1; J.doNorm = 1;
      J.W = P.W_ac; J.addm = P.preHF;
      J.out = P.preHF; J.N = H4_;
      J.m0 = (bid >> 5) * 64; J.n0 = (bid & 31) * 64;
      gemm64<16>(J, tid, AsL, BsL, scl, shf);
    }
    gbar(P.arr, ++g);

    // ---------- PhF: gates + in-block BN -> c, h, out[t] ----------
    if (bid < 64) {
      const int gc = bid * 8;
      const int r = tid >> 1, sub = tid & 1;
      const float* pb = P.preHF + (size_t)r * H4_ + gc + sub * 4;
      f4 pA = ld_c(pb);
      f4 pF = ld_c(pb + 512);
      f4 pI = ld_c(pb + 1024);
      f4 pO = ld_c(pb + 1536);
      f4 cn, hv;
      #pragma unroll
      for (int i = 0; i < 4; ++i) {
        float iv = tanhf(pA[i]);
        float fg = sigf(pF[i]), ig = sigf(pI[i]), og = sigf(pO[i]);
        cn[i] = iv * ig + creg[i] * fg;
        hv[i] = og * eluf(cn[i]);
      }
      creg = cn;
      st_c(P.c + (size_t)r * H_ + gc + sub * 4, cn);
      f4* rS = (f4*)AsL;   // 512 f4 = 8KB scratch
      f4* rQ = (f4*)BsL;
      rS[tid] = hv; rQ[tid] = hv * hv;
      __syncthreads();
      for (int off = 256; off >= 2; off >>= 1) {
        if (tid < off) { rS[tid] += rS[tid + off]; rQ[tid] += rQ[tid + off]; }
        __syncthreads();
      }
      if (tid < 8) {
        float S = rS[tid >> 2][tid & 3], Q = rQ[tid >> 2][tid & 3];
        float mu = S * (1.f / B_), var = Q * (1.f / B_) - mu * mu;
        float sc = rsqrtf(var + EPS_) * P.g_post[gc + tid];
        scl[tid] = sc; shf[tid] = P.be_post[gc + tid] - mu * sc;
      }
      __syncthreads();
      f4 hn;
      #pragma unroll
      for (int i = 0; i < 4; ++i) hn[i] = hv[i] * scl[sub * 4 + i] + shf[sub * 4 + i];
      st_c(P.h + (size_t)r * H_ + gc + sub * 4, hn);
      *(f4*)&P.out[(size_t)t * BH_ + (size_t)r * H_ + gc + sub * 4] = hn;
    }
    gbar(P.arr, ++g);
  }
}

#define SYNC_UINTS (NBLK * FSTRIDE)

__global__ __launch_bounds__(256) void pinit(float* c, float* h, unsigned* sync) {
  const int i = blockIdx.x * 256 + threadIdx.x;
  if (i < BH_) { c[i] = 0.f; h[i] = 0.f; }
  if (i < SYNC_UINTS) sync[i] = 0u;
}

extern "C" void kernel_launch(void* const* d_in, const int* in_sizes, int n_in,
                              void* d_out, int out_size, void* d_ws, size_t ws_size,
                              hipStream_t stream) {
  Params P;
  P.x      = (const float*)d_in[0];
  P.W_ih   = (const float*)d_in[1];
  P.b_ih   = (const float*)d_in[2];
  P.W_hh   = (const float*)d_in[3];
  P.Wq_in  = (const float*)d_in[4];
  P.bq_in  = (const float*)d_in[5];
  P.Wq     = (const float*)d_in[6];
  P.bq     = (const float*)d_in[7];
  P.Wk     = (const float*)d_in[8];
  P.bk     = (const float*)d_in[9];
  P.Wv     = (const float*)d_in[10];
  P.bv     = (const float*)d_in[11];
  P.Wo     = (const float*)d_in[12];
  P.bo     = (const float*)d_in[13];
  P.W_ac   = (const float*)d_in[14];
  P.b_ac   = (const float*)d_in[15];
  P.g_att  = (const float*)d_in[16];
  P.be_att = (const float*)d_in[17];
  P.g_post = (const float*)d_in[18];
  P.be_post= (const float*)d_in[19];
  P.out    = (float*)d_out;

  unsigned* sync = (unsigned*)d_ws;
  P.arr = sync;
  float* fb = (float*)d_ws + SYNC_UINTS;
  P.c     = fb; fb += BH_;
  P.h     = fb; fb += BH_;
  P.q     = fb; fb += BH_;
  P.Qh    = fb; fb += BH_;
  P.ctx   = fb; fb += BH_;
  P.attp  = fb; fb += BH_;
  P.preHF = fb; fb += (size_t)B_ * H4_;
  P.Kbuf  = fb; fb += (size_t)W_ * BH_;
  P.Vbuf  = fb; fb += (size_t)W_ * BH_;
  P.preXb0= fb; fb += (size_t)B_ * H4_;
  P.preXb1= fb; fb += (size_t)B_ * H4_;
  P.qXb0  = fb; fb += BH_;
  P.qXb1  = fb; fb += BH_;
  P.stA   = fb; fb += 4096;

  pinit<<<(BH_ + 255) / 256, 256, 0, stream>>>(P.c, P.h, sync);
  larnn<<<NBLK, NTHR, 0, stream>>>(P);
}